// Round 19
// baseline (153.829 us; speedup 1.0000x reference)
//
#include <hip/hip_runtime.h>
#include <hip/hip_fp16.h>

#define DIN 128
#define H1  64
#define H2  32
#define NCH 512      // sort chunks
#define BSH 8        // bucket = dst >> BSH (256 nodes/bucket)

typedef _Float16 f16x8 __attribute__((ext_vector_type(8)));
typedef _Float16 f16x4 __attribute__((ext_vector_type(4)));
typedef float    f32x4 __attribute__((ext_vector_type(4)));

// ---- chunk histogram by bucket (LDS only, no global atomics) ----
__global__ __launch_bounds__(256) void k_hist(const int* __restrict__ dst,
        int* __restrict__ H, int E, int NB, int chunk) {
    __shared__ int lh[512];
    int c = blockIdx.x, tid = threadIdx.x;
    for (int b = tid; b < NB; b += 256) lh[b] = 0;
    __syncthreads();
    int e0 = c * chunk, e1 = min(E, e0 + chunk);
    for (int e = e0 + tid; e < e1; e += 256)
        atomicAdd(&lh[dst[e] >> BSH], 1);
    __syncthreads();
    for (int b = tid; b < NB; b += 256) H[(size_t)b * NCH + c] = lh[b];
}

// ---- scan step 1: per-block (1024 elems) exclusive scan + block totals ----
__global__ __launch_bounds__(256) void k_scan1(const int* __restrict__ in,
        int* __restrict__ out, int* __restrict__ partial, int N) {
    int tid = threadIdx.x;
    int base = blockIdx.x * 1024 + tid * 4;
    int v0 = (base + 0 < N) ? in[base + 0] : 0;
    int v1 = (base + 1 < N) ? in[base + 1] : 0;
    int v2 = (base + 2 < N) ? in[base + 2] : 0;
    int v3 = (base + 3 < N) ? in[base + 3] : 0;
    int sum = v0 + v1 + v2 + v3;
    int lane = tid & 63, wid = tid >> 6;
    int x = sum;
#pragma unroll
    for (int off = 1; off < 64; off <<= 1) {
        int y = __shfl_up(x, off, 64);
        if (lane >= off) x += y;
    }
    __shared__ int wsum[4];
    if (lane == 63) wsum[wid] = x;
    __syncthreads();
    int wbase = 0;
    for (int w = 0; w < wid; ++w) wbase += wsum[w];
    int excl = wbase + x - sum;
    if (base + 0 < N) out[base + 0] = excl;
    if (base + 1 < N) out[base + 1] = excl + v0;
    if (base + 2 < N) out[base + 2] = excl + v0 + v1;
    if (base + 3 < N) out[base + 3] = excl + v0 + v1 + v2;
    if (tid == 0) partial[blockIdx.x] = wsum[0] + wsum[1] + wsum[2] + wsum[3];
}

// ---- scan step 2: one-block exclusive scan of block totals (nb <= 256) ----
__global__ __launch_bounds__(256) void k_scan2(int* __restrict__ partial, int nb) {
    int tid = threadIdx.x;
    int v = (tid < nb) ? partial[tid] : 0;
    __shared__ int tmp[256];
    tmp[tid] = v;
    __syncthreads();
    for (int off = 1; off < 256; off <<= 1) {
        int y = (tid >= off) ? tmp[tid - off] : 0;
        __syncthreads();
        tmp[tid] += y;
        __syncthreads();
    }
    if (tid < nb) partial[tid] = tmp[tid] - v;   // exclusive
}

// ---- scan step 3: add block offsets ----
__global__ void k_scan3b(int* __restrict__ a, const int* __restrict__ partial, int n) {
    int i = blockIdx.x * blockDim.x + threadIdx.x;
    if (i < n) a[i] += partial[i >> 10];
}

// ---- bucket sort: chunk c writes its edges into bucket-grouped packed ep ----
//      packed word = src | (dst_local << 20)   (needs N < 2^20, BSH <= 11)
__global__ __launch_bounds__(256) void k_bsort(const int* __restrict__ src,
        const int* __restrict__ dst, const int* __restrict__ H,
        int* __restrict__ ep, int E, int NB, int chunk) {
    __shared__ int cur[512];
    int c = blockIdx.x, tid = threadIdx.x;
    for (int b = tid; b < NB; b += 256) cur[b] = H[(size_t)b * NCH + c];
    __syncthreads();
    int e0 = c * chunk, e1 = min(E, e0 + chunk);
    for (int e = e0 + tid; e < e1; e += 256) {
        int s = src[e], d = dst[e];
        int pos = atomicAdd(&cur[d >> BSH], 1);
        ep[pos] = s | ((d & ((1 << BSH) - 1)) << 20);
    }
}

// ---- CSR finalize A: per-bucket degree count + 8-aligned local scan ----
__global__ __launch_bounds__(256) void k_csrA(const int* __restrict__ ep,
        const int* __restrict__ H, int* __restrict__ degi, float* __restrict__ dinv,
        int* __restrict__ lexcl, int* __restrict__ btot, int E, int N, int NB) {
    __shared__ int cnt[256], wsum[4];
    int b = blockIdx.x, tid = threadIdx.x;
    cnt[tid] = 0;
    int bstart = H[(size_t)b * NCH];
    int bend = (b + 1 < NB) ? H[(size_t)(b + 1) * NCH] : E;
    __syncthreads();
    for (int e = bstart + tid; e < bend; e += 256)
        atomicAdd(&cnt[ep[e] >> 20], 1);
    __syncthreads();
    int v = cnt[tid];
    int n = (b << BSH) + tid;
    int d8 = (n < N) ? ((v + 7) & ~7) : 0;       // 8-aligned slot size
    int lane = tid & 63, wid = tid >> 6;
    int x = d8;
#pragma unroll
    for (int off = 1; off < 64; off <<= 1) {
        int y = __shfl_up(x, off, 64);
        if (lane >= off) x += y;
    }
    if (lane == 63) wsum[wid] = x;
    __syncthreads();
    int wbase = 0;
    for (int w = 0; w < wid; ++w) wbase += wsum[w];
    int excl = wbase + x - d8;                   // exclusive aligned prefix
    if (n < N) {
        degi[n]  = v;
        dinv[n]  = rsqrtf((float)v + 1.0f);
        lexcl[n] = excl;
    }
    if (tid == 0) btot[b] = wsum[0] + wsum[1] + wsum[2] + wsum[3];
}

// ---- bucket-total exclusive scan (nb <= 512), one block ----
__global__ __launch_bounds__(256) void k_scanC(int* __restrict__ a, int nb) {
    int tid = threadIdx.x;
    int i0 = 2 * tid, i1 = 2 * tid + 1;
    int v0 = (i0 < nb) ? a[i0] : 0;
    int v1 = (i1 < nb) ? a[i1] : 0;
    int p = v0 + v1;
    __shared__ int tmp[256];
    tmp[tid] = p;
    __syncthreads();
    for (int off = 1; off < 256; off <<= 1) {
        int y = (tid >= off) ? tmp[tid - off] : 0;
        __syncthreads();
        tmp[tid] += y;
        __syncthreads();
    }
    int excl = tmp[tid] - p;
    if (i0 < nb) a[i0] = excl;
    if (i1 < nb) a[i1] = excl + v0;
}

// ---- CSR finalize B: final aligned rowptr, scatter, pad-fill with N ----
__global__ __launch_bounds__(256) void k_csrB(const int* __restrict__ ep,
        const int* __restrict__ H, const int* __restrict__ degi,
        const int* __restrict__ bbase, const int* __restrict__ lexcl,
        int* __restrict__ rowptr, int* __restrict__ csr_src, int E, int N, int NB) {
    __shared__ int pos[256];
    int b = blockIdx.x, tid = threadIdx.x;
    int bstart = H[(size_t)b * NCH];
    int bend = (b + 1 < NB) ? H[(size_t)(b + 1) * NCH] : E;
    int n = (b << BSH) + tid;
    int startv = 0;
    if (n < N) {
        startv = bbase[b] + lexcl[n];            // multiple of 8
        rowptr[n] = startv;
    }
    pos[tid] = startv;
    __syncthreads();
    for (int e = bstart + tid; e < bend; e += 256) {
        int p = ep[e];
        int q = atomicAdd(&pos[p >> 20], 1);
        csr_src[q] = p & 0xFFFFF;
    }
    __syncthreads();
    if (n < N) {
        int d = degi[n], d8 = (d + 7) & ~7;
        for (int z = startv + d; z < startv + d8; ++z)
            csr_src[z] = N;                      // pad -> zero row
    }
}

// ---- MFMA GEMM layer 1: t1h(fp16)[N][64] = (x @ W1) * dinv ----
__global__ __launch_bounds__(256) void k_mgemm1(const float* __restrict__ x,
        const float* __restrict__ W1, const float* __restrict__ dinv,
        _Float16* __restrict__ t1h, int N) {
    __shared__ _Float16 sA[64 * 128];   // 16 KB, row 256 B, XOR-swizzled
    __shared__ _Float16 sB[64 * 128];   // 16 KB, sB[n][k] = W1[k][n], swizzled
    int tid = threadIdx.x;
    int row0 = blockIdx.x * 64;
    if (blockIdx.x == 0 && tid < 8)      // zero row N (gather pad target)
        ((f32x4*)(t1h + (size_t)N * H1))[tid] = (f32x4){0.f, 0.f, 0.f, 0.f};
#pragma unroll
    for (int i = 0; i < 8; ++i) {
        int idx4 = tid + 256 * i;        // 0..2047 float4 slots
        int r = idx4 >> 5, c4 = idx4 & 31;
        int row = row0 + r;
        float4 v = make_float4(0.f, 0.f, 0.f, 0.f);
        if (row < N) v = *(const float4*)&x[(size_t)row * DIN + c4 * 4];
        f16x4 h;
        h[0] = (_Float16)v.x; h[1] = (_Float16)v.y;
        h[2] = (_Float16)v.z; h[3] = (_Float16)v.w;
        int byte = (c4 * 8) ^ ((r & 7) << 4);
        *(f16x4*)((char*)sA + r * 256 + byte) = h;
    }
    {
        int n = tid & 63, kq = tid >> 6;  // kq 0..3, 32 k each
        _Float16 tmp[32];
#pragma unroll
        for (int kk = 0; kk < 32; ++kk)
            tmp[kk] = (_Float16)W1[(size_t)(kq * 32 + kk) * H1 + n];
#pragma unroll
        for (int j = 0; j < 4; ++j) {
            int byte = ((kq * 32 + j * 8) * 2) ^ ((n & 7) << 4);
            *(f16x8*)((char*)sB + n * 256 + byte) = *(f16x8*)&tmp[j * 8];
        }
    }
    __syncthreads();
    int lane = tid & 63, w = tid >> 6;
    int lr = lane & 15, kg = lane >> 4;
    f32x4 acc[4] = {};
    int ar = w * 16 + lr;
    const char* pa = (const char*)sA + ar * 256;
    int axor = (ar & 7) << 4;
#pragma unroll
    for (int ks = 0; ks < 4; ++ks) {
        int kb = ks * 64 + kg * 16;
        f16x8 a = *(const f16x8*)(pa + (kb ^ axor));
#pragma unroll
        for (int nt = 0; nt < 4; ++nt) {
            int bn = nt * 16 + lr;
            f16x8 b = *(const f16x8*)((const char*)sB + bn * 256 + (kb ^ ((bn & 7) << 4)));
            acc[nt] = __builtin_amdgcn_mfma_f32_16x16x32_f16(a, b, acc[nt], 0, 0, 0);
        }
    }
#pragma unroll
    for (int rg = 0; rg < 4; ++rg) {
        int R = row0 + w * 16 + kg * 4 + rg;
        if (R < N) {
            float dv = dinv[R];
#pragma unroll
            for (int nt = 0; nt < 4; ++nt)
                t1h[(size_t)R * H1 + nt * 16 + lr] = (_Float16)(acc[nt][rg] * dv);
        }
    }
}

// ---- MFMA GEMM layer 2: t2h(fp16)[N][32] = (agg1h @ W2) * dinv ----
__global__ __launch_bounds__(256) void k_mgemm2(const _Float16* __restrict__ aggh,
        const float* __restrict__ W2, const float* __restrict__ dinv,
        _Float16* __restrict__ t2h, int N) {
    __shared__ _Float16 sA[64 * 64];    // 8 KB
    __shared__ _Float16 sB[32 * 64];    // 4 KB
    int tid = threadIdx.x;
    int row0 = blockIdx.x * 64;
    if (blockIdx.x == 0 && tid < 4)      // zero row N (gather pad target)
        ((f32x4*)(t2h + (size_t)N * H2))[tid] = (f32x4){0.f, 0.f, 0.f, 0.f};
#pragma unroll
    for (int i = 0; i < 2; ++i) {
        int idx8 = tid + 256 * i;        // 0..511 f16x8 chunks
        int r = idx8 >> 3, c8 = idx8 & 7;
        int row = row0 + r;
        f16x8 h = {};
        if (row < N) h = *(const f16x8*)&aggh[(size_t)row * H1 + c8 * 8];
        int byte = (c8 * 16) ^ ((r & 7) << 4);
        *(f16x8*)((char*)sA + r * 128 + byte) = h;
    }
    {
        int n = tid & 31, kq = tid >> 5;  // kq 0..7, 8 k each
        _Float16 tmp[8];
#pragma unroll
        for (int kk = 0; kk < 8; ++kk)
            tmp[kk] = (_Float16)W2[(size_t)(kq * 8 + kk) * H2 + n];
        int byte = (kq * 16) ^ ((n & 7) << 4);
        *(f16x8*)((char*)sB + n * 128 + byte) = *(f16x8*)&tmp[0];
    }
    __syncthreads();
    int lane = tid & 63, w = tid >> 6;
    int lr = lane & 15, kg = lane >> 4;
    f32x4 acc[2] = {};
    int ar = w * 16 + lr;
    const char* pa = (const char*)sA + ar * 128;
    int axor = (ar & 7) << 4;
#pragma unroll
    for (int ks = 0; ks < 2; ++ks) {
        int kb = ks * 64 + kg * 16;
        f16x8 a = *(const f16x8*)(pa + (kb ^ axor));
#pragma unroll
        for (int nt = 0; nt < 2; ++nt) {
            int bn = nt * 16 + lr;
            f16x8 b = *(const f16x8*)((const char*)sB + bn * 128 + (kb ^ ((bn & 7) << 4)));
            acc[nt] = __builtin_amdgcn_mfma_f32_16x16x32_f16(a, b, acc[nt], 0, 0, 0);
        }
    }
#pragma unroll
    for (int rg = 0; rg < 4; ++rg) {
        int R = row0 + w * 16 + kg * 4 + rg;
        if (R < N) {
            float dv = dinv[R];
#pragma unroll
            for (int nt = 0; nt < 2; ++nt)
                t2h[(size_t)R * H2 + nt * 16 + lr] = (_Float16)(acc[nt][rg] * dv);
        }
    }
}

// ---- pull aggregation: 1<<LOGL lanes/node, 16B NON-TEMPORAL gathers, no masks ----
// CSR is 8-aligned per node; pad entries index the zero row N -> add 0.
// nt-flagged gathers skip L1 allocation (0% hit rate anyway) to dodge the
// per-CU outstanding-miss (MSHR) cap hypothesized from r11-r18's constant time.
template <int LOGL, bool FUSE>
__global__ __launch_bounds__(256) void k_aggq(const int* __restrict__ rowptr,
        const int* __restrict__ degi, const int* __restrict__ csr_src,
        const float* __restrict__ dinv, const _Float16* __restrict__ tp,
        void* __restrict__ outv, int N) {
    const int L = 1 << LOGL;                 // lanes per node
    const int F = L * 8;                     // feats per row
    int local = threadIdx.x >> LOGL;
    int j = threadIdx.x & (L - 1);           // 16B slice index
    int n = blockIdx.x * (256 >> LOGL) + local;
    if (n >= N) return;
    int start = rowptr[n];                   // multiple of 8
    int deg = degi[n];
    f16x8 sv = *(const f16x8*)&tp[(size_t)n * F + j * 8];
    float acc[8];
#pragma unroll
    for (int t = 0; t < 8; ++t) acc[t] = (float)sv[t];
    for (int k = 0; k < deg; k += 8) {
        int4 ra = *(const int4*)&csr_src[start + k];
        int4 rb = *(const int4*)&csr_src[start + k + 4];
        int idx[8] = {ra.x, ra.y, ra.z, ra.w, rb.x, rb.y, rb.z, rb.w};
        f16x8 g[8];
#pragma unroll
        for (int u = 0; u < 8; ++u)
            g[u] = __builtin_nontemporal_load(
                (const f16x8*)&tp[(size_t)idx[u] * F + j * 8]);
#pragma unroll
        for (int u = 0; u < 8; ++u)
#pragma unroll
            for (int t = 0; t < 8; ++t)
                acc[t] += (float)g[u][t];
    }
    float dv = dinv[n];
    if (FUSE) {                              // fp16(relu(acc*dinv)) -> 16B store
        f16x8 o;
#pragma unroll
        for (int t = 0; t < 8; ++t) o[t] = (_Float16)fmaxf(acc[t] * dv, 0.f);
        *(f16x8*)((_Float16*)outv + (size_t)n * F + j * 8) = o;
    } else {                                 // fp32 -> 2x float4 store
        float* op = (float*)outv + (size_t)n * F + j * 8;
        f32x4 o0 = {acc[0] * dv, acc[1] * dv, acc[2] * dv, acc[3] * dv};
        f32x4 o1 = {acc[4] * dv, acc[5] * dv, acc[6] * dv, acc[7] * dv};
        *(f32x4*)op = o0;
        *(f32x4*)(op + 4) = o1;
    }
}

extern "C" void kernel_launch(void* const* d_in, const int* in_sizes, int n_in,
                              void* d_out, int out_size, void* d_ws, size_t ws_size,
                              hipStream_t stream) {
    const float* x  = (const float*)d_in[0];
    const int*   ei = (const int*)d_in[1];
    const float* W1 = (const float*)d_in[2];
    const float* W2 = (const float*)d_in[3];

    const int N = in_sizes[0] / DIN;   // 100000 (< 2^20, required by ep packing)
    const int E = in_sizes[1] / 2;     // 1600000
    const int* src = ei;
    const int* dst = ei + E;

    const int NB    = (N + (1 << BSH) - 1) >> BSH;   // 391 buckets
    const int NBNCH = NB * NCH;                       // 200192
    const int chunk = (E + NCH - 1) / NCH;            // 3125

    // workspace layout (4-byte elems unless noted)
    float*    dinv    = (float*)d_ws;                     // N
    int*      degi    = (int*)(dinv + N);                 // N
    int*      rowptr  = degi + N;                         // N
    int*      lexcl   = rowptr + N;                       // N
    int*      H       = lexcl + N;                        // NB*NCH
    int*      partial = H + NBNCH;                        // 256
    int*      btot    = partial + 256;                    // 512
    int*      csr_src = btot + 512;                       // E + 8N (aligned slots)
    _Float16* t1h     = (_Float16*)(csr_src + E + 8 * N); // (N+1)*64 halves
    _Float16* agg1h   = t1h + (size_t)(N + 1) * H1;       // N*64 halves
    _Float16* t2h     = t1h;                              // (N+1)*32, reuse
    float*    out     = (float*)d_out;                    // N*32 fp32
    int*      ep      = (int*)t1h;                        // E packed ints, consumed
                                                          // by k_csrA/B pre-gemm1

    // --- counting-sort CSR build (8-aligned rows, no global atomics) ---
    k_hist<<<NCH, 256, 0, stream>>>(dst, H, E, NB, chunk);
    k_scan1<<<(NBNCH + 1023) / 1024, 256, 0, stream>>>(H, H, partial, NBNCH);
    k_scan2<<<1, 256, 0, stream>>>(partial, (NBNCH + 1023) / 1024);
    k_scan3b<<<(NBNCH + 255) / 256, 256, 0, stream>>>(H, partial, NBNCH);
    k_bsort<<<NCH, 256, 0, stream>>>(src, dst, H, ep, E, NB, chunk);
    k_csrA<<<NB, 256, 0, stream>>>(ep, H, degi, dinv, lexcl, btot, E, N, NB);
    k_scanC<<<1, 256, 0, stream>>>(btot, NB);
    k_csrB<<<NB, 256, 0, stream>>>(ep, H, degi, btot, lexcl, rowptr, csr_src, E, N, NB);

    const int ntile = (N + 63) / 64;                 // 1563

    // --- layer 1 ---
    k_mgemm1<<<ntile, 256, 0, stream>>>(x, W1, dinv, t1h, N);
    k_aggq<3, true><<<(N + 31) / 32, 256, 0, stream>>>(rowptr, degi, csr_src, dinv,
                                                       t1h, agg1h, N);

    // --- layer 2 ---
    k_mgemm2<<<ntile, 256, 0, stream>>>(agg1h, W2, dinv, t2h, N);
    k_aggq<2, false><<<(N + 63) / 64, 256, 0, stream>>>(rowptr, degi, csr_src, dinv,
                                                        t2h, out, N);
}

// Round 20
// 128.802 us; speedup vs baseline: 1.1943x; 1.1943x over previous
//
#include <hip/hip_runtime.h>
#include <hip/hip_fp16.h>

#define DIN 128
#define H1  64
#define H2  32
#define NCH 512      // sort chunks
#define BSH 8        // bucket = dst >> BSH (256 nodes/bucket)

typedef _Float16 f16x8 __attribute__((ext_vector_type(8)));
typedef _Float16 f16x4 __attribute__((ext_vector_type(4)));
typedef float    f32x4 __attribute__((ext_vector_type(4)));

// ---- chunk histogram by bucket (LDS only, no global atomics) ----
__global__ __launch_bounds__(256) void k_hist(const int* __restrict__ dst,
        int* __restrict__ H, int E, int NB, int chunk) {
    __shared__ int lh[512];
    int c = blockIdx.x, tid = threadIdx.x;
    for (int b = tid; b < NB; b += 256) lh[b] = 0;
    __syncthreads();
    int e0 = c * chunk, e1 = min(E, e0 + chunk);
    for (int e = e0 + tid; e < e1; e += 256)
        atomicAdd(&lh[dst[e] >> BSH], 1);
    __syncthreads();
    for (int b = tid; b < NB; b += 256) H[(size_t)b * NCH + c] = lh[b];
}

// ---- scan step 1: per-block (1024 elems) exclusive scan + block totals ----
__global__ __launch_bounds__(256) void k_scan1(const int* __restrict__ in,
        int* __restrict__ out, int* __restrict__ partial, int N) {
    int tid = threadIdx.x;
    int base = blockIdx.x * 1024 + tid * 4;
    int v0 = (base + 0 < N) ? in[base + 0] : 0;
    int v1 = (base + 1 < N) ? in[base + 1] : 0;
    int v2 = (base + 2 < N) ? in[base + 2] : 0;
    int v3 = (base + 3 < N) ? in[base + 3] : 0;
    int sum = v0 + v1 + v2 + v3;
    int lane = tid & 63, wid = tid >> 6;
    int x = sum;
#pragma unroll
    for (int off = 1; off < 64; off <<= 1) {
        int y = __shfl_up(x, off, 64);
        if (lane >= off) x += y;
    }
    __shared__ int wsum[4];
    if (lane == 63) wsum[wid] = x;
    __syncthreads();
    int wbase = 0;
    for (int w = 0; w < wid; ++w) wbase += wsum[w];
    int excl = wbase + x - sum;
    if (base + 0 < N) out[base + 0] = excl;
    if (base + 1 < N) out[base + 1] = excl + v0;
    if (base + 2 < N) out[base + 2] = excl + v0 + v1;
    if (base + 3 < N) out[base + 3] = excl + v0 + v1 + v2;
    if (tid == 0) partial[blockIdx.x] = wsum[0] + wsum[1] + wsum[2] + wsum[3];
}

// ---- scan step 2: one-block exclusive scan of block totals (nb <= 256) ----
__global__ __launch_bounds__(256) void k_scan2(int* __restrict__ partial, int nb) {
    int tid = threadIdx.x;
    int v = (tid < nb) ? partial[tid] : 0;
    __shared__ int tmp[256];
    tmp[tid] = v;
    __syncthreads();
    for (int off = 1; off < 256; off <<= 1) {
        int y = (tid >= off) ? tmp[tid - off] : 0;
        __syncthreads();
        tmp[tid] += y;
        __syncthreads();
    }
    if (tid < nb) partial[tid] = tmp[tid] - v;   // exclusive
}

// ---- scan step 3: add block offsets ----
__global__ void k_scan3b(int* __restrict__ a, const int* __restrict__ partial, int n) {
    int i = blockIdx.x * blockDim.x + threadIdx.x;
    if (i < n) a[i] += partial[i >> 10];
}

// ---- bucket sort: chunk c writes its edges into bucket-grouped packed ep ----
//      packed word = src | (dst_local << 20)   (needs N < 2^20, BSH <= 11)
__global__ __launch_bounds__(256) void k_bsort(const int* __restrict__ src,
        const int* __restrict__ dst, const int* __restrict__ H,
        int* __restrict__ ep, int E, int NB, int chunk) {
    __shared__ int cur[512];
    int c = blockIdx.x, tid = threadIdx.x;
    for (int b = tid; b < NB; b += 256) cur[b] = H[(size_t)b * NCH + c];
    __syncthreads();
    int e0 = c * chunk, e1 = min(E, e0 + chunk);
    for (int e = e0 + tid; e < e1; e += 256) {
        int s = src[e], d = dst[e];
        int pos = atomicAdd(&cur[d >> BSH], 1);
        ep[pos] = s | ((d & ((1 << BSH) - 1)) << 20);
    }
}

// ---- CSR finalize A: per-bucket degree count + 8-aligned local scan ----
__global__ __launch_bounds__(256) void k_csrA(const int* __restrict__ ep,
        const int* __restrict__ H, int* __restrict__ degi, float* __restrict__ dinv,
        int* __restrict__ lexcl, int* __restrict__ btot, int E, int N, int NB) {
    __shared__ int cnt[256], wsum[4];
    int b = blockIdx.x, tid = threadIdx.x;
    cnt[tid] = 0;
    int bstart = H[(size_t)b * NCH];
    int bend = (b + 1 < NB) ? H[(size_t)(b + 1) * NCH] : E;
    __syncthreads();
    for (int e = bstart + tid; e < bend; e += 256)
        atomicAdd(&cnt[ep[e] >> 20], 1);
    __syncthreads();
    int v = cnt[tid];
    int n = (b << BSH) + tid;
    int d8 = (n < N) ? ((v + 7) & ~7) : 0;       // 8-aligned slot size
    int lane = tid & 63, wid = tid >> 6;
    int x = d8;
#pragma unroll
    for (int off = 1; off < 64; off <<= 1) {
        int y = __shfl_up(x, off, 64);
        if (lane >= off) x += y;
    }
    if (lane == 63) wsum[wid] = x;
    __syncthreads();
    int wbase = 0;
    for (int w = 0; w < wid; ++w) wbase += wsum[w];
    int excl = wbase + x - d8;                   // exclusive aligned prefix
    if (n < N) {
        degi[n]  = v;
        dinv[n]  = rsqrtf((float)v + 1.0f);
        lexcl[n] = excl;
    }
    if (tid == 0) btot[b] = wsum[0] + wsum[1] + wsum[2] + wsum[3];
}

// ---- bucket-total exclusive scan (nb <= 512), one block ----
__global__ __launch_bounds__(256) void k_scanC(int* __restrict__ a, int nb) {
    int tid = threadIdx.x;
    int i0 = 2 * tid, i1 = 2 * tid + 1;
    int v0 = (i0 < nb) ? a[i0] : 0;
    int v1 = (i1 < nb) ? a[i1] : 0;
    int p = v0 + v1;
    __shared__ int tmp[256];
    tmp[tid] = p;
    __syncthreads();
    for (int off = 1; off < 256; off <<= 1) {
        int y = (tid >= off) ? tmp[tid - off] : 0;
        __syncthreads();
        tmp[tid] += y;
        __syncthreads();
    }
    int excl = tmp[tid] - p;
    if (i0 < nb) a[i0] = excl;
    if (i1 < nb) a[i1] = excl + v0;
}

// ---- CSR finalize B: final aligned rowptr, scatter, pad-fill with N ----
__global__ __launch_bounds__(256) void k_csrB(const int* __restrict__ ep,
        const int* __restrict__ H, const int* __restrict__ degi,
        const int* __restrict__ bbase, const int* __restrict__ lexcl,
        int* __restrict__ rowptr, int* __restrict__ csr_src, int E, int N, int NB) {
    __shared__ int pos[256];
    int b = blockIdx.x, tid = threadIdx.x;
    int bstart = H[(size_t)b * NCH];
    int bend = (b + 1 < NB) ? H[(size_t)(b + 1) * NCH] : E;
    int n = (b << BSH) + tid;
    int startv = 0;
    if (n < N) {
        startv = bbase[b] + lexcl[n];            // multiple of 8
        rowptr[n] = startv;
    }
    pos[tid] = startv;
    __syncthreads();
    for (int e = bstart + tid; e < bend; e += 256) {
        int p = ep[e];
        int q = atomicAdd(&pos[p >> 20], 1);
        csr_src[q] = p & 0xFFFFF;
    }
    __syncthreads();
    if (n < N) {
        int d = degi[n], d8 = (d + 7) & ~7;
        for (int z = startv + d; z < startv + d8; ++z)
            csr_src[z] = N;                      // pad -> zero row
    }
}

// ---- MFMA GEMM layer 1: t1h(fp16)[N][64] = (x @ W1) * dinv ----
__global__ __launch_bounds__(256) void k_mgemm1(const float* __restrict__ x,
        const float* __restrict__ W1, const float* __restrict__ dinv,
        _Float16* __restrict__ t1h, int N) {
    __shared__ _Float16 sA[64 * 128];   // 16 KB, row 256 B, XOR-swizzled
    __shared__ _Float16 sB[64 * 128];   // 16 KB, sB[n][k] = W1[k][n], swizzled
    int tid = threadIdx.x;
    int row0 = blockIdx.x * 64;
    if (blockIdx.x == 0 && tid < 8)      // zero row N (gather pad target)
        ((f32x4*)(t1h + (size_t)N * H1))[tid] = (f32x4){0.f, 0.f, 0.f, 0.f};
#pragma unroll
    for (int i = 0; i < 8; ++i) {
        int idx4 = tid + 256 * i;        // 0..2047 float4 slots
        int r = idx4 >> 5, c4 = idx4 & 31;
        int row = row0 + r;
        float4 v = make_float4(0.f, 0.f, 0.f, 0.f);
        if (row < N) v = *(const float4*)&x[(size_t)row * DIN + c4 * 4];
        f16x4 h;
        h[0] = (_Float16)v.x; h[1] = (_Float16)v.y;
        h[2] = (_Float16)v.z; h[3] = (_Float16)v.w;
        int byte = (c4 * 8) ^ ((r & 7) << 4);
        *(f16x4*)((char*)sA + r * 256 + byte) = h;
    }
    {
        int n = tid & 63, kq = tid >> 6;  // kq 0..3, 32 k each
        _Float16 tmp[32];
#pragma unroll
        for (int kk = 0; kk < 32; ++kk)
            tmp[kk] = (_Float16)W1[(size_t)(kq * 32 + kk) * H1 + n];
#pragma unroll
        for (int j = 0; j < 4; ++j) {
            int byte = ((kq * 32 + j * 8) * 2) ^ ((n & 7) << 4);
            *(f16x8*)((char*)sB + n * 256 + byte) = *(f16x8*)&tmp[j * 8];
        }
    }
    __syncthreads();
    int lane = tid & 63, w = tid >> 6;
    int lr = lane & 15, kg = lane >> 4;
    f32x4 acc[4] = {};
    int ar = w * 16 + lr;
    const char* pa = (const char*)sA + ar * 256;
    int axor = (ar & 7) << 4;
#pragma unroll
    for (int ks = 0; ks < 4; ++ks) {
        int kb = ks * 64 + kg * 16;
        f16x8 a = *(const f16x8*)(pa + (kb ^ axor));
#pragma unroll
        for (int nt = 0; nt < 4; ++nt) {
            int bn = nt * 16 + lr;
            f16x8 b = *(const f16x8*)((const char*)sB + bn * 256 + (kb ^ ((bn & 7) << 4)));
            acc[nt] = __builtin_amdgcn_mfma_f32_16x16x32_f16(a, b, acc[nt], 0, 0, 0);
        }
    }
#pragma unroll
    for (int rg = 0; rg < 4; ++rg) {
        int R = row0 + w * 16 + kg * 4 + rg;
        if (R < N) {
            float dv = dinv[R];
#pragma unroll
            for (int nt = 0; nt < 4; ++nt)
                t1h[(size_t)R * H1 + nt * 16 + lr] = (_Float16)(acc[nt][rg] * dv);
        }
    }
}

// ---- MFMA GEMM layer 2: t2h(fp16)[N][32] = (agg1h @ W2) * dinv ----
__global__ __launch_bounds__(256) void k_mgemm2(const _Float16* __restrict__ aggh,
        const float* __restrict__ W2, const float* __restrict__ dinv,
        _Float16* __restrict__ t2h, int N) {
    __shared__ _Float16 sA[64 * 64];    // 8 KB
    __shared__ _Float16 sB[32 * 64];    // 4 KB
    int tid = threadIdx.x;
    int row0 = blockIdx.x * 64;
    if (blockIdx.x == 0 && tid < 4)      // zero row N (gather pad target)
        ((f32x4*)(t2h + (size_t)N * H2))[tid] = (f32x4){0.f, 0.f, 0.f, 0.f};
#pragma unroll
    for (int i = 0; i < 2; ++i) {
        int idx8 = tid + 256 * i;        // 0..511 f16x8 chunks
        int r = idx8 >> 3, c8 = idx8 & 7;
        int row = row0 + r;
        f16x8 h = {};
        if (row < N) h = *(const f16x8*)&aggh[(size_t)row * H1 + c8 * 8];
        int byte = (c8 * 16) ^ ((r & 7) << 4);
        *(f16x8*)((char*)sA + r * 128 + byte) = h;
    }
    {
        int n = tid & 31, kq = tid >> 5;  // kq 0..7, 8 k each
        _Float16 tmp[8];
#pragma unroll
        for (int kk = 0; kk < 8; ++kk)
            tmp[kk] = (_Float16)W2[(size_t)(kq * 8 + kk) * H2 + n];
        int byte = (kq * 16) ^ ((n & 7) << 4);
        *(f16x8*)((char*)sB + n * 128 + byte) = *(f16x8*)&tmp[0];
    }
    __syncthreads();
    int lane = tid & 63, w = tid >> 6;
    int lr = lane & 15, kg = lane >> 4;
    f32x4 acc[2] = {};
    int ar = w * 16 + lr;
    const char* pa = (const char*)sA + ar * 128;
    int axor = (ar & 7) << 4;
#pragma unroll
    for (int ks = 0; ks < 2; ++ks) {
        int kb = ks * 64 + kg * 16;
        f16x8 a = *(const f16x8*)(pa + (kb ^ axor));
#pragma unroll
        for (int nt = 0; nt < 2; ++nt) {
            int bn = nt * 16 + lr;
            f16x8 b = *(const f16x8*)((const char*)sB + bn * 128 + (kb ^ ((bn & 7) << 4)));
            acc[nt] = __builtin_amdgcn_mfma_f32_16x16x32_f16(a, b, acc[nt], 0, 0, 0);
        }
    }
#pragma unroll
    for (int rg = 0; rg < 4; ++rg) {
        int R = row0 + w * 16 + kg * 4 + rg;
        if (R < N) {
            float dv = dinv[R];
#pragma unroll
            for (int nt = 0; nt < 2; ++nt)
                t2h[(size_t)R * H2 + nt * 16 + lr] = (_Float16)(acc[nt][rg] * dv);
        }
    }
}

// ---- pull aggregation: 1<<LOGL lanes/node, 16B gathers, no masks ----
// CSR is 8-aligned per node; pad entries index the zero row N -> add 0.
// Indices loaded as 2x int4 per 8-edge batch.
template <int LOGL, bool FUSE>
__global__ __launch_bounds__(256) void k_aggq(const int* __restrict__ rowptr,
        const int* __restrict__ degi, const int* __restrict__ csr_src,
        const float* __restrict__ dinv, const _Float16* __restrict__ tp,
        void* __restrict__ outv, int N) {
    const int L = 1 << LOGL;                 // lanes per node
    const int F = L * 8;                     // feats per row
    int local = threadIdx.x >> LOGL;
    int j = threadIdx.x & (L - 1);           // 16B slice index
    int n = blockIdx.x * (256 >> LOGL) + local;
    if (n >= N) return;
    int start = rowptr[n];                   // multiple of 8
    int deg = degi[n];
    f16x8 sv = *(const f16x8*)&tp[(size_t)n * F + j * 8];
    float acc[8];
#pragma unroll
    for (int t = 0; t < 8; ++t) acc[t] = (float)sv[t];
    for (int k = 0; k < deg; k += 8) {
        int4 ra = *(const int4*)&csr_src[start + k];
        int4 rb = *(const int4*)&csr_src[start + k + 4];
        int idx[8] = {ra.x, ra.y, ra.z, ra.w, rb.x, rb.y, rb.z, rb.w};
        f16x8 g[8];
#pragma unroll
        for (int u = 0; u < 8; ++u)
            g[u] = *(const f16x8*)&tp[(size_t)idx[u] * F + j * 8];
#pragma unroll
        for (int u = 0; u < 8; ++u)
#pragma unroll
            for (int t = 0; t < 8; ++t)
                acc[t] += (float)g[u][t];
    }
    float dv = dinv[n];
    if (FUSE) {                              // fp16(relu(acc*dinv)) -> 16B store
        f16x8 o;
#pragma unroll
        for (int t = 0; t < 8; ++t) o[t] = (_Float16)fmaxf(acc[t] * dv, 0.f);
        *(f16x8*)((_Float16*)outv + (size_t)n * F + j * 8) = o;
    } else {                                 // fp32 -> 2x float4 store
        float* op = (float*)outv + (size_t)n * F + j * 8;
        f32x4 o0 = {acc[0] * dv, acc[1] * dv, acc[2] * dv, acc[3] * dv};
        f32x4 o1 = {acc[4] * dv, acc[5] * dv, acc[6] * dv, acc[7] * dv};
        *(f32x4*)op = o0;
        *(f32x4*)(op + 4) = o1;
    }
}

extern "C" void kernel_launch(void* const* d_in, const int* in_sizes, int n_in,
                              void* d_out, int out_size, void* d_ws, size_t ws_size,
                              hipStream_t stream) {
    const float* x  = (const float*)d_in[0];
    const int*   ei = (const int*)d_in[1];
    const float* W1 = (const float*)d_in[2];
    const float* W2 = (const float*)d_in[3];

    const int N = in_sizes[0] / DIN;   // 100000 (< 2^20, required by ep packing)
    const int E = in_sizes[1] / 2;     // 1600000
    const int* src = ei;
    const int* dst = ei + E;

    const int NB    = (N + (1 << BSH) - 1) >> BSH;   // 391 buckets
    const int NBNCH = NB * NCH;                       // 200192
    const int chunk = (E + NCH - 1) / NCH;            // 3125

    // workspace layout (4-byte elems unless noted)
    float*    dinv    = (float*)d_ws;                     // N
    int*      degi    = (int*)(dinv + N);                 // N
    int*      rowptr  = degi + N;                         // N
    int*      lexcl   = rowptr + N;                       // N
    int*      H       = lexcl + N;                        // NB*NCH
    int*      partial = H + NBNCH;                        // 256
    int*      btot    = partial + 256;                    // 512
    int*      csr_src = btot + 512;                       // E + 8N (aligned slots)
    _Float16* t1h     = (_Float16*)(csr_src + E + 8 * N); // (N+1)*64 halves
    _Float16* agg1h   = t1h + (size_t)(N + 1) * H1;       // N*64 halves
    _Float16* t2h     = t1h;                              // (N+1)*32, reuse
    float*    out     = (float*)d_out;                    // N*32 fp32
    int*      ep      = (int*)t1h;                        // E packed ints, consumed
                                                          // by k_csrA/B pre-gemm1

    // --- counting-sort CSR build (8-aligned rows, no global atomics) ---
    k_hist<<<NCH, 256, 0, stream>>>(dst, H, E, NB, chunk);
    k_scan1<<<(NBNCH + 1023) / 1024, 256, 0, stream>>>(H, H, partial, NBNCH);
    k_scan2<<<1, 256, 0, stream>>>(partial, (NBNCH + 1023) / 1024);
    k_scan3b<<<(NBNCH + 255) / 256, 256, 0, stream>>>(H, partial, NBNCH);
    k_bsort<<<NCH, 256, 0, stream>>>(src, dst, H, ep, E, NB, chunk);
    k_csrA<<<NB, 256, 0, stream>>>(ep, H, degi, dinv, lexcl, btot, E, N, NB);
    k_scanC<<<1, 256, 0, stream>>>(btot, NB);
    k_csrB<<<NB, 256, 0, stream>>>(ep, H, degi, btot, lexcl, rowptr, csr_src, E, N, NB);

    const int ntile = (N + 63) / 64;                 // 1563

    // --- layer 1 ---
    k_mgemm1<<<ntile, 256, 0, stream>>>(x, W1, dinv, t1h, N);
    k_aggq<3, true><<<(N + 31) / 32, 256, 0, stream>>>(rowptr, degi, csr_src, dinv,
                                                       t1h, agg1h, N);

    // --- layer 2 ---
    k_mgemm2<<<ntile, 256, 0, stream>>>(agg1h, W2, dinv, t2h, N);
    k_aggq<2, false><<<(N + 63) / 64, 256, 0, stream>>>(rowptr, degi, csr_src, dinv,
                                                        t2h, out, N);
}